// Round 1
// baseline (611.239 us; speedup 1.0000x reference)
//
#include <hip/hip_runtime.h>
#include <hip/hip_cooperative_groups.h>
#include <stdint.h>

namespace cg = cooperative_groups;

// Problem shape (fixed by setup_inputs)
#define BB 64
#define CC 128
#define HW 3136
#define NPR (CC * HW)        // 401408 elements per batch row
#define NBINS 8192
#define BIN_SHIFT 19         // key >> 19 -> top 13 bits (sign + 8 exp + 4 mantissa)
#define KEY_LOW 0x7FFFFu     // low 19 key bits (all candidates share the top 13)
#define GRID (BB * 16)       // 1024 blocks = 256 CU x 4 blocks/CU (co-resident)
#define SELCAP 4096          // select-phase LDS compaction capacity (32 KiB)

typedef float vf4 __attribute__((ext_vector_type(4)));  // native vector for nontemporal

// Workspace layout (bytes):
//   [512, 1536)     : rowmeta int2[64]  {binstar, E}
//   [2048, 2304)    : counters u32[64]
//   [4096, 4096+2MB): hist u32[64][8192]
//   [CAND_OFF, ...) : candidates u64[64][cap]  (packed (key&0x7FFFF)<<32 | ~idx)
#define ROWMETA_OFF 512
#define COUNTER_OFF 2048
#define HIST_OFF 4096
#define CAND_OFF (HIST_OFF + (size_t)BB * NBINS * 4)

__device__ __forceinline__ uint32_t tokey(float b) {
    uint32_t u = __float_as_uint(b);
    return u ^ (uint32_t)(((int32_t)u >> 31) | 0x80000000);
}

__device__ __forceinline__ float boostf(const float* dc, int c, int K) {
    float td = (float)((double)K / (double)NPR);   // jnp.float32(k/n)
    float d = td - dc[c];
    return (float)exp((double)d);
}

// Single shared pool: phases reuse the same LDS (union keeps static size = max phase).
// sizeof = select struct ~34.8 KB -> 4 blocks/CU = 139 KB <= 160 KB.
union SMem {
    struct { uint32_t lh[NBINS]; float sbf[8]; } h;                       // phase 1
    struct { uint32_t csum[256]; } sc;                                    // phase 2
    struct { float sbf[8]; uint32_t lcnt, gbase;
             unsigned long long lbuf[2048]; } w;                          // phase 3
    struct { uint32_t hist[256]; uint32_t sufs[256];
             unsigned long long buf[SELCAP];
             uint32_t scnt; int sh_d, sh_done; } s;                       // phase 4
};

// =============== fused cooperative kernel: all 4 stages + init =================
__global__ __launch_bounds__(256, 4) void k_fused(const float* __restrict__ x,
                                                  const float* __restrict__ dc,
                                                  const int* __restrict__ kptr,
                                                  float* __restrict__ out,
                                                  unsigned long long* __restrict__ cand,
                                                  uint32_t* __restrict__ counters,
                                                  uint32_t* __restrict__ hist,
                                                  int2* __restrict__ rowmeta,
                                                  int cap) {
    cg::grid_group grid = cg::this_grid();
    __shared__ SMem sm;
    const int tid = threadIdx.x;
    const int blk = blockIdx.x;
    const int row = blk >> 4;                      // 64 rows x 16 groups of 8 channels
    const int c0 = (blk & 15) * 8;
    const int K = *kptr;
    const int nf4 = 8 * HW / 4;                    // 6272 (784 f4 per channel)

    // ---- phase 0: zero hist / counters / rowmeta (replaces hipMemsetAsync) ----
    {
        const int total = BB * NBINS;              // 524288 words
        for (int i = blk * 256 + tid; i < total; i += GRID * 256) hist[i] = 0;
        if (blk == 0 && tid < BB) { counters[tid] = 0u; rowmeta[tid] = make_int2(0, 0); }
    }
    grid.sync();

    // ---- phase 1: per-row histogram (LDS privatized, sparse global flush) ----
    {
        for (int i = tid; i < NBINS; i += 256) sm.h.lh[i] = 0;
        if (tid < 8) sm.h.sbf[tid] = boostf(dc, c0 + tid, K);
        __syncthreads();
        const float4* xp = (const float4*)(x + (size_t)row * NPR + (size_t)c0 * HW);
        int t = tid;
        for (; t + 256 < nf4; t += 512) {          // 2-way unrolled, independent loads
            float4 a = xp[t];
            float4 b = xp[t + 256];
            float fa = sm.h.sbf[t / 784];
            float fb = sm.h.sbf[(t + 256) / 784];
            atomicAdd(&sm.h.lh[tokey(a.x * fa) >> BIN_SHIFT], 1u);
            atomicAdd(&sm.h.lh[tokey(a.y * fa) >> BIN_SHIFT], 1u);
            atomicAdd(&sm.h.lh[tokey(a.z * fa) >> BIN_SHIFT], 1u);
            atomicAdd(&sm.h.lh[tokey(a.w * fa) >> BIN_SHIFT], 1u);
            atomicAdd(&sm.h.lh[tokey(b.x * fb) >> BIN_SHIFT], 1u);
            atomicAdd(&sm.h.lh[tokey(b.y * fb) >> BIN_SHIFT], 1u);
            atomicAdd(&sm.h.lh[tokey(b.z * fb) >> BIN_SHIFT], 1u);
            atomicAdd(&sm.h.lh[tokey(b.w * fb) >> BIN_SHIFT], 1u);
        }
        if (t < nf4) {
            float4 a = xp[t];
            float fa = sm.h.sbf[t / 784];
            atomicAdd(&sm.h.lh[tokey(a.x * fa) >> BIN_SHIFT], 1u);
            atomicAdd(&sm.h.lh[tokey(a.y * fa) >> BIN_SHIFT], 1u);
            atomicAdd(&sm.h.lh[tokey(a.z * fa) >> BIN_SHIFT], 1u);
            atomicAdd(&sm.h.lh[tokey(a.w * fa) >> BIN_SHIFT], 1u);
        }
        __syncthreads();
        uint32_t* gh = hist + (size_t)row * NBINS;
        for (int i = tid; i < NBINS; i += 256) {
            uint32_t v = sm.h.lh[i];
            if (v) atomicAdd(&gh[i], v);           // sparse flush: ~200 hot bins
        }
    }
    grid.sync();

    // ---- phase 2: find boundary bin per row (blocks 0..63 only) -------------
    if (blk < BB) {
        const uint32_t* gh = hist + (size_t)blk * NBINS;
        uint32_t Ku = (uint32_t)K;
        int hi = NBINS - 1 - 32 * tid;             // chunk covers [hi-31, hi], descending
        uint32_t ssum = 0;
        for (int j = 0; j < 32; j++) ssum += gh[hi - j];
        sm.sc.csum[tid] = ssum;
        __syncthreads();
        for (int off = 1; off < 256; off <<= 1) {  // inclusive scan, descending-bin order
            uint32_t v = (tid >= off) ? sm.sc.csum[tid - off] : 0u;
            __syncthreads();
            sm.sc.csum[tid] += v;
            __syncthreads();
        }
        uint32_t incl = sm.sc.csum[tid];
        uint32_t excl = incl - ssum;
        if (excl < Ku && incl >= Ku) {             // exactly one thread
            uint32_t cum = excl;
            for (int j = 0; j < 32; j++) {
                int b = hi - j;
                uint32_t h = gh[b];
                if (cum + h >= Ku) { rowmeta[blk] = make_int2(b, (int)(Ku - cum)); break; }
                cum += h;
            }
        }
    }
    grid.sync();

    // ---- phase 3: write clear winners/zeros, compact boundary bin -----------
    {
        int bstar = rowmeta[row].x;
        if (tid == 0) sm.w.lcnt = 0;
        if (tid < 8) sm.w.sbf[tid] = boostf(dc, c0 + tid, K);
        __syncthreads();

        size_t base = (size_t)row * NPR + (size_t)c0 * HW;
        const float4* xp = (const float4*)(x + base);   // L3-resident after phase 1
        vf4* op = (vf4*)(out + base);
        int jbase = c0 * HW;

        int t = tid;
        for (; t + 256 < nf4; t += 512) {
            float4 a = xp[t];
            float4 b = xp[t + 256];
            float fa = sm.w.sbf[t / 784];
            float fb = sm.w.sbf[(t + 256) / 784];
            vf4 oa, ob;
            float* ai = (float*)&a;
            float* bi = (float*)&b;
            #pragma unroll
            for (int q = 0; q < 4; q++) {
                float xv = ai[q];
                uint32_t key = tokey(xv * fa);
                int bin = (int)(key >> BIN_SHIFT);
                oa[q] = (bin > bstar) ? xv : 0.0f;
                if (bin == bstar) {
                    uint32_t j = (uint32_t)(jbase + 4 * t + q);
                    unsigned long long packed =
                        ((unsigned long long)(key & KEY_LOW) << 32) | (uint32_t)(~j);
                    uint32_t pos = atomicAdd(&sm.w.lcnt, 1u);
                    if (pos < 2048u) sm.w.lbuf[pos] = packed;
                    else {
                        uint32_t gp = atomicAdd(&counters[row], 1u);
                        if ((int)gp < cap) cand[(size_t)row * cap + gp] = packed;
                    }
                }
            }
            #pragma unroll
            for (int q = 0; q < 4; q++) {
                float xv = bi[q];
                uint32_t key = tokey(xv * fb);
                int bin = (int)(key >> BIN_SHIFT);
                ob[q] = (bin > bstar) ? xv : 0.0f;
                if (bin == bstar) {
                    uint32_t j = (uint32_t)(jbase + 4 * (t + 256) + q);
                    unsigned long long packed =
                        ((unsigned long long)(key & KEY_LOW) << 32) | (uint32_t)(~j);
                    uint32_t pos = atomicAdd(&sm.w.lcnt, 1u);
                    if (pos < 2048u) sm.w.lbuf[pos] = packed;
                    else {
                        uint32_t gp = atomicAdd(&counters[row], 1u);
                        if ((int)gp < cap) cand[(size_t)row * cap + gp] = packed;
                    }
                }
            }
            __builtin_nontemporal_store(oa, &op[t]);       // keep x resident in L3
            __builtin_nontemporal_store(ob, &op[t + 256]);
        }
        if (t < nf4) {
            float4 a = xp[t];
            float fa = sm.w.sbf[t / 784];
            vf4 oa;
            float* ai = (float*)&a;
            #pragma unroll
            for (int q = 0; q < 4; q++) {
                float xv = ai[q];
                uint32_t key = tokey(xv * fa);
                int bin = (int)(key >> BIN_SHIFT);
                oa[q] = (bin > bstar) ? xv : 0.0f;
                if (bin == bstar) {
                    uint32_t j = (uint32_t)(jbase + 4 * t + q);
                    unsigned long long packed =
                        ((unsigned long long)(key & KEY_LOW) << 32) | (uint32_t)(~j);
                    uint32_t pos = atomicAdd(&sm.w.lcnt, 1u);
                    if (pos < 2048u) sm.w.lbuf[pos] = packed;
                    else {
                        uint32_t gp = atomicAdd(&counters[row], 1u);
                        if ((int)gp < cap) cand[(size_t)row * cap + gp] = packed;
                    }
                }
            }
            __builtin_nontemporal_store(oa, &op[t]);
        }
        __syncthreads();
        uint32_t m = sm.w.lcnt < 2048u ? sm.w.lcnt : 2048u;
        if (tid == 0) sm.w.gbase = atomicAdd(&counters[row], m);
        __syncthreads();
        for (uint32_t i = tid; i < m; i += 256) {
            uint32_t pos = sm.w.gbase + i;
            if ((int)pos < cap) cand[(size_t)row * cap + pos] = sm.w.lbuf[i];
        }
    }
    grid.sync();

    // ---- phase 4: exact radix-select among candidates + scatter (blocks 0..63)
    if (blk < BB) {
        uint32_t cnt = counters[blk];
        if ((int)cnt > cap) cnt = (uint32_t)cap;
        int E = rowmeta[blk].y;
        const unsigned long long* cp = cand + (size_t)blk * cap;

        unsigned long long prefix = 0ull, mask = 0ull, thr = 0ull;
        uint32_t remaining = (uint32_t)E;
        bool compacted = false;
        uint32_t csize = cnt;
        if (tid == 0) sm.s.sh_done = 0;

        for (int shift = 48; shift >= 0; shift -= 8) {
            sm.s.hist[tid] = 0;
            __syncthreads();
            if (!compacted) {
                for (uint32_t s = tid; s < cnt; s += 256) {
                    unsigned long long v = cp[s];
                    if ((v & mask) == prefix)
                        atomicAdd(&sm.s.hist[(uint32_t)(v >> shift) & 255u], 1u);
                }
            } else {
                for (uint32_t s = tid; s < csize; s += 256)
                    atomicAdd(&sm.s.hist[(uint32_t)(sm.s.buf[s] >> shift) & 255u], 1u);
            }
            __syncthreads();
            sm.s.sufs[tid] = sm.s.hist[tid];
            __syncthreads();
            for (int off = 1; off < 256; off <<= 1) {   // suffix sums (descending scan)
                uint32_t add = (tid + off < 256) ? sm.s.sufs[tid + off] : 0u;
                __syncthreads();
                sm.s.sufs[tid] += add;
                __syncthreads();
            }
            {
                uint32_t sd = sm.s.sufs[tid];
                uint32_t sn = (tid < 255) ? sm.s.sufs[tid + 1] : 0u;
                if (sd >= remaining && sn < remaining) sm.s.sh_d = tid;
            }
            __syncthreads();
            int d = sm.s.sh_d;
            uint32_t cumG = (d < 255) ? sm.s.sufs[d + 1] : 0u;
            uint32_t binC = sm.s.sufs[d] - cumG;
            unsigned long long npref = prefix | ((unsigned long long)(uint32_t)d << shift);
            unsigned long long nmask = mask | (0xFFull << shift);
            bool done = (sm.s.sufs[d] == remaining);    // whole bin completes exactly
            if (done) {
                thr = npref;
                if (tid == 0) sm.s.sh_done = 1;
            }
            remaining -= cumG;
            __syncthreads();                            // sufs reads done; sh_done visible
            if (!sm.s.sh_done && binC <= (uint32_t)SELCAP && shift > 0) {
                if (tid == 0) sm.s.scnt = 0;
                __syncthreads();
                // Survivors at any stage are exactly {v : (v & nmask)==npref} over the
                // global list, so compaction always refilters from global (cnt is tiny).
                for (uint32_t s = tid; s < cnt; s += 256) {
                    unsigned long long v = cp[s];
                    if ((v & nmask) == npref) {
                        uint32_t p = atomicAdd(&sm.s.scnt, 1u);
                        sm.s.buf[p] = v;
                    }
                }
                __syncthreads();
                csize = binC;
                compacted = true;
            }
            prefix = npref;
            mask = nmask;
            if (sm.s.sh_done) break;
        }
        if (!sm.s.sh_done) thr = prefix;               // fully resolved (all v distinct)

        const float* xr = x + (size_t)blk * NPR;
        float* orow = out + (size_t)blk * NPR;
        for (uint32_t s = tid; s < cnt; s += 256) {
            unsigned long long v = cp[s];
            if (v >= thr) {
                uint32_t j = ~(uint32_t)v;
                orow[j] = xr[j];
            }
        }
    }
}

// ====================== fallback: original 4-kernel pipeline ===================
__global__ __launch_bounds__(256) void k_hist(const float* __restrict__ x,
                                              const float* __restrict__ dc,
                                              const int* __restrict__ kptr,
                                              uint32_t* __restrict__ hist) {
    __shared__ uint32_t lh[NBINS];
    __shared__ float sbf[8];
    for (int i = threadIdx.x; i < NBINS; i += 256) lh[i] = 0;
    if (threadIdx.x < 8) {
        int c0 = (blockIdx.x & 15) * 8;
        sbf[threadIdx.x] = boostf(dc, c0 + threadIdx.x, *kptr);
    }
    __syncthreads();
    int row = blockIdx.x >> 4;
    int c0 = (blockIdx.x & 15) * 8;
    const float4* xp = (const float4*)(x + (size_t)row * NPR + (size_t)c0 * HW);
    const int nf4 = 8 * HW / 4;
    int t = threadIdx.x;
    for (; t + 256 < nf4; t += 512) {
        float4 a = xp[t];
        float4 b = xp[t + 256];
        float fa = sbf[t / 784];
        float fb = sbf[(t + 256) / 784];
        atomicAdd(&lh[tokey(a.x * fa) >> BIN_SHIFT], 1u);
        atomicAdd(&lh[tokey(a.y * fa) >> BIN_SHIFT], 1u);
        atomicAdd(&lh[tokey(a.z * fa) >> BIN_SHIFT], 1u);
        atomicAdd(&lh[tokey(a.w * fa) >> BIN_SHIFT], 1u);
        atomicAdd(&lh[tokey(b.x * fb) >> BIN_SHIFT], 1u);
        atomicAdd(&lh[tokey(b.y * fb) >> BIN_SHIFT], 1u);
        atomicAdd(&lh[tokey(b.z * fb) >> BIN_SHIFT], 1u);
        atomicAdd(&lh[tokey(b.w * fb) >> BIN_SHIFT], 1u);
    }
    if (t < nf4) {
        float4 a = xp[t];
        float fa = sbf[t / 784];
        atomicAdd(&lh[tokey(a.x * fa) >> BIN_SHIFT], 1u);
        atomicAdd(&lh[tokey(a.y * fa) >> BIN_SHIFT], 1u);
        atomicAdd(&lh[tokey(a.z * fa) >> BIN_SHIFT], 1u);
        atomicAdd(&lh[tokey(a.w * fa) >> BIN_SHIFT], 1u);
    }
    __syncthreads();
    uint32_t* gh = hist + (size_t)row * NBINS;
    for (int i = threadIdx.x; i < NBINS; i += 256) {
        uint32_t v = lh[i];
        if (v) atomicAdd(&gh[i], v);
    }
}

__global__ __launch_bounds__(256) void k_scan(const uint32_t* __restrict__ hist,
                                              const int* __restrict__ kptr,
                                              int2* __restrict__ rowmeta) {
    int row = blockIdx.x;
    const uint32_t* gh = hist + (size_t)row * NBINS;
    uint32_t K = (uint32_t)(*kptr);
    __shared__ uint32_t csum[256];
    int t = threadIdx.x;
    int hi = NBINS - 1 - 32 * t;
    uint32_t s = 0;
    for (int j = 0; j < 32; j++) s += gh[hi - j];
    csum[t] = s;
    __syncthreads();
    for (int off = 1; off < 256; off <<= 1) {
        uint32_t v = (t >= off) ? csum[t - off] : 0u;
        __syncthreads();
        csum[t] += v;
        __syncthreads();
    }
    uint32_t incl = csum[t];
    uint32_t excl = incl - s;
    if (excl < K && incl >= K) {
        uint32_t cum = excl;
        for (int j = 0; j < 32; j++) {
            int b = hi - j;
            uint32_t h = gh[b];
            if (cum + h >= K) { rowmeta[row] = make_int2(b, (int)(K - cum)); break; }
            cum += h;
        }
    }
}

__global__ __launch_bounds__(256) void k_write(const float* __restrict__ x,
                                               const float* __restrict__ dc,
                                               const int* __restrict__ kptr,
                                               const int2* __restrict__ rowmeta,
                                               float* __restrict__ out,
                                               unsigned long long* __restrict__ cand,
                                               uint32_t* __restrict__ counters,
                                               int cap) {
    int row = blockIdx.x >> 4;
    int c0 = (blockIdx.x & 15) * 8;
    int bstar = rowmeta[row].x;
    __shared__ float sbf[8];
    __shared__ uint32_t lcnt;
    __shared__ uint32_t gbase;
    __shared__ unsigned long long lbuf[2048];
    if (threadIdx.x == 0) lcnt = 0;
    if (threadIdx.x < 8) sbf[threadIdx.x] = boostf(dc, c0 + threadIdx.x, *kptr);
    __syncthreads();
    size_t base = (size_t)row * NPR + (size_t)c0 * HW;
    const float4* xp = (const float4*)(x + base);
    vf4* op = (vf4*)(out + base);
    int jbase = c0 * HW;
    const int nf4 = 8 * HW / 4;
    int t = threadIdx.x;
    for (; t + 256 < nf4; t += 512) {
        float4 a = xp[t];
        float4 b = xp[t + 256];
        float fa = sbf[t / 784];
        float fb = sbf[(t + 256) / 784];
        vf4 oa, ob;
        float* ai = (float*)&a;
        float* bi = (float*)&b;
        #pragma unroll
        for (int q = 0; q < 4; q++) {
            float xv = ai[q];
            uint32_t key = tokey(xv * fa);
            int bin = (int)(key >> BIN_SHIFT);
            oa[q] = (bin > bstar) ? xv : 0.0f;
            if (bin == bstar) {
                uint32_t j = (uint32_t)(jbase + 4 * t + q);
                unsigned long long packed =
                    ((unsigned long long)(key & KEY_LOW) << 32) | (uint32_t)(~j);
                uint32_t pos = atomicAdd(&lcnt, 1u);
                if (pos < 2048u) lbuf[pos] = packed;
                else {
                    uint32_t gp = atomicAdd(&counters[row], 1u);
                    if ((int)gp < cap) cand[(size_t)row * cap + gp] = packed;
                }
            }
        }
        #pragma unroll
        for (int q = 0; q < 4; q++) {
            float xv = bi[q];
            uint32_t key = tokey(xv * fb);
            int bin = (int)(key >> BIN_SHIFT);
            ob[q] = (bin > bstar) ? xv : 0.0f;
            if (bin == bstar) {
                uint32_t j = (uint32_t)(jbase + 4 * (t + 256) + q);
                unsigned long long packed =
                    ((unsigned long long)(key & KEY_LOW) << 32) | (uint32_t)(~j);
                uint32_t pos = atomicAdd(&lcnt, 1u);
                if (pos < 2048u) lbuf[pos] = packed;
                else {
                    uint32_t gp = atomicAdd(&counters[row], 1u);
                    if ((int)gp < cap) cand[(size_t)row * cap + gp] = packed;
                }
            }
        }
        __builtin_nontemporal_store(oa, &op[t]);
        __builtin_nontemporal_store(ob, &op[t + 256]);
    }
    if (t < nf4) {
        float4 a = xp[t];
        float fa = sbf[t / 784];
        vf4 oa;
        float* ai = (float*)&a;
        #pragma unroll
        for (int q = 0; q < 4; q++) {
            float xv = ai[q];
            uint32_t key = tokey(xv * fa);
            int bin = (int)(key >> BIN_SHIFT);
            oa[q] = (bin > bstar) ? xv : 0.0f;
            if (bin == bstar) {
                uint32_t j = (uint32_t)(jbase + 4 * t + q);
                unsigned long long packed =
                    ((unsigned long long)(key & KEY_LOW) << 32) | (uint32_t)(~j);
                uint32_t pos = atomicAdd(&lcnt, 1u);
                if (pos < 2048u) lbuf[pos] = packed;
                else {
                    uint32_t gp = atomicAdd(&counters[row], 1u);
                    if ((int)gp < cap) cand[(size_t)row * cap + gp] = packed;
                }
            }
        }
        __builtin_nontemporal_store(oa, &op[t]);
    }
    __syncthreads();
    uint32_t m = lcnt < 2048u ? lcnt : 2048u;
    if (threadIdx.x == 0) gbase = atomicAdd(&counters[row], m);
    __syncthreads();
    for (uint32_t i = threadIdx.x; i < m; i += 256) {
        uint32_t pos = gbase + i;
        if ((int)pos < cap) cand[(size_t)row * cap + pos] = lbuf[i];
    }
}

__global__ __launch_bounds__(1024) void k_select(const float* __restrict__ x,
                                                 float* __restrict__ out,
                                                 const unsigned long long* __restrict__ cand,
                                                 const uint32_t* __restrict__ counters,
                                                 const int2* __restrict__ rowmeta,
                                                 int cap) {
    int row = blockIdx.x;
    uint32_t cnt = counters[row];
    if ((int)cnt > cap) cnt = (uint32_t)cap;
    int E = rowmeta[row].y;
    const unsigned long long* cp = cand + (size_t)row * cap;
    int tid = threadIdx.x;
    __shared__ uint32_t hist[256];
    __shared__ uint32_t sufs[256];
    __shared__ unsigned long long buf[6144];
    __shared__ uint32_t scnt;
    __shared__ int sh_d, sh_done;
    unsigned long long prefix = 0ull, mask = 0ull, thr = 0ull;
    uint32_t remaining = (uint32_t)E;
    bool compacted = false;
    uint32_t csize = cnt;
    if (tid == 0) sh_done = 0;
    for (int shift = 48; shift >= 0; shift -= 8) {
        if (tid < 256) hist[tid] = 0;
        __syncthreads();
        if (!compacted) {
            for (uint32_t s = tid; s < cnt; s += 1024) {
                unsigned long long v = cp[s];
                if ((v & mask) == prefix)
                    atomicAdd(&hist[(uint32_t)(v >> shift) & 255u], 1u);
            }
        } else {
            for (uint32_t s = tid; s < csize; s += 1024)
                atomicAdd(&hist[(uint32_t)(buf[s] >> shift) & 255u], 1u);
        }
        __syncthreads();
        if (tid < 256) sufs[tid] = hist[tid];
        __syncthreads();
        for (int off = 1; off < 256; off <<= 1) {
            uint32_t add = 0;
            if (tid < 256 && tid + off < 256) add = sufs[tid + off];
            __syncthreads();
            if (tid < 256) sufs[tid] += add;
            __syncthreads();
        }
        if (tid < 256) {
            uint32_t sd = sufs[tid];
            uint32_t sn = (tid < 255) ? sufs[tid + 1] : 0u;
            if (sd >= remaining && sn < remaining) sh_d = tid;
        }
        __syncthreads();
        int d = sh_d;
        uint32_t cumG = (d < 255) ? sufs[d + 1] : 0u;
        uint32_t binC = sufs[d] - cumG;
        unsigned long long npref = prefix | ((unsigned long long)(uint32_t)d << shift);
        bool done = (sufs[d] == remaining);
        if (done) {
            thr = npref;
            if (tid == 0) sh_done = 1;
        }
        remaining -= cumG;
        __syncthreads();
        if (!sh_done && binC <= 6144u && shift > 0) {
            if (tid == 0) scnt = 0;
            unsigned long long keep[6]; int nk = 0;
            if (compacted) {
                for (uint32_t s = tid; s < csize; s += 1024) {
                    unsigned long long v = buf[s];
                    if (((uint32_t)(v >> shift) & 255u) == (uint32_t)d) {
                        if (nk < 6) keep[nk++] = v;
                    }
                }
            }
            __syncthreads();
            if (!compacted) {
                for (uint32_t s = tid; s < cnt; s += 1024) {
                    unsigned long long v = cp[s];
                    if ((v & mask) == prefix &&
                        ((uint32_t)(v >> shift) & 255u) == (uint32_t)d) {
                        uint32_t p = atomicAdd(&scnt, 1u);
                        buf[p] = v;
                    }
                }
            } else if (nk > 0) {
                uint32_t p = atomicAdd(&scnt, (uint32_t)nk);
                for (int i = 0; i < nk; i++) buf[p + i] = keep[i];
            }
            __syncthreads();
            csize = binC;
            compacted = true;
        }
        prefix = npref;
        mask |= (0xFFull << shift);
        if (sh_done) break;
    }
    if (!sh_done) thr = prefix;
    const float* xr = x + (size_t)row * NPR;
    float* orow = out + (size_t)row * NPR;
    for (uint32_t s = tid; s < cnt; s += 1024) {
        unsigned long long v = cp[s];
        if (v >= thr) {
            uint32_t j = ~(uint32_t)v;
            orow[j] = xr[j];
        }
    }
}

extern "C" void kernel_launch(void* const* d_in, const int* in_sizes, int n_in,
                              void* d_out, int out_size, void* d_ws, size_t ws_size,
                              hipStream_t stream) {
    const float* x  = (const float*)d_in[0];
    const float* dc = (const float*)d_in[1];
    const int* kptr = (const int*)d_in[2];
    float* out = (float*)d_out;

    char* ws = (char*)d_ws;
    int2* rowmeta       = (int2*)(ws + ROWMETA_OFF);
    uint32_t* counters  = (uint32_t*)(ws + COUNTER_OFF);
    uint32_t* hist      = (uint32_t*)(ws + HIST_OFF);
    unsigned long long* cand = (unsigned long long*)(ws + CAND_OFF);

    size_t cap_sz = (ws_size > CAND_OFF) ? (ws_size - CAND_OFF) / ((size_t)BB * 8) : 0;
    if (cap_sz > 65536) cap_sz = 65536;
    int cap = (int)cap_sz;

    void* args[] = {(void*)&x, (void*)&dc, (void*)&kptr, (void*)&out, (void*)&cand,
                    (void*)&counters, (void*)&hist, (void*)&rowmeta, (void*)&cap};
    hipError_t err = hipLaunchCooperativeKernel((void*)k_fused, dim3(GRID), dim3(256),
                                                args, 0, stream);
    if (err != hipSuccess) {
        // Fallback: original 4-kernel pipeline (identical semantics).
        (void)hipMemsetAsync(ws, 0, CAND_OFF, stream);
        k_hist<<<BB * 16, 256, 0, stream>>>(x, dc, kptr, hist);
        k_scan<<<BB, 256, 0, stream>>>(hist, kptr, rowmeta);
        k_write<<<BB * 16, 256, 0, stream>>>(x, dc, kptr, rowmeta, out, cand, counters, cap);
        k_select<<<BB, 1024, 0, stream>>>(x, out, cand, counters, rowmeta, cap);
    }
}

// Round 2
// 391.714 us; speedup vs baseline: 1.5604x; 1.5604x over previous
//
#include <hip/hip_runtime.h>
#include <stdint.h>

// Problem shape (fixed by setup_inputs)
#define BB 64
#define CC 128
#define HW 3136
#define NPR (CC * HW)        // 401408 elements per batch row
#define NBINS 8192
#define BIN_SHIFT 19         // key >> 19 -> top 13 bits (sign + 8 exp + 4 mantissa)
#define KEY_LOW 0x7FFFFu     // low 19 key bits (all candidates share the top 13)
#define SELCAP 2048          // select compaction buffer (reuses lbuf)

typedef float vf4 __attribute__((ext_vector_type(4)));  // native vector for nontemporal

// Workspace layout (bytes):
//   [512, 1536)     : rowmeta int2[64]  {binstar, E}
//   [1536, 1792)    : harr u32[64]   (k_hist_scan arrival counters)
//   [2048, 2304)    : counters u32[64]
//   [2560, 2816)    : warr u32[64]   (k_write_sel arrival counters)
//   [4096, 4096+2MB): hist u32[64][8192]
//   [CAND_OFF, ...) : candidates u64[64][cap]  (packed (key&0x7FFFF)<<32 | ~idx)
#define ROWMETA_OFF 512
#define HARR_OFF 1536
#define COUNTER_OFF 2048
#define WARR_OFF 2560
#define HIST_OFF 4096
#define CAND_OFF (HIST_OFF + (size_t)BB * NBINS * 4)

__device__ __forceinline__ uint32_t tokey(float b) {
    uint32_t u = __float_as_uint(b);
    return u ^ (uint32_t)(((int32_t)u >> 31) | 0x80000000);
}

__device__ __forceinline__ float boostf(const float* dc, int c, int K) {
    float td = (float)((double)K / (double)NPR);   // jnp.float32(k/n)
    float d = td - dc[c];
    return (float)exp((double)d);
}

// Agent-scope (device-coherent) accesses for intra-dispatch cross-XCD sharing.
__device__ __forceinline__ uint32_t aload32(const uint32_t* p) {
    return __hip_atomic_load(p, __ATOMIC_RELAXED, __HIP_MEMORY_SCOPE_AGENT);
}
__device__ __forceinline__ unsigned long long aload64(const unsigned long long* p) {
    return __hip_atomic_load(p, __ATOMIC_RELAXED, __HIP_MEMORY_SCOPE_AGENT);
}
__device__ __forceinline__ void astore64(unsigned long long* p, unsigned long long v) {
    __hip_atomic_store(p, v, __ATOMIC_RELAXED, __HIP_MEMORY_SCOPE_AGENT);
}

// ======== kernel 1: per-row histogram (u16-packed LDS, 8 blocks/CU) =========
// Last-arriving block of each row also computes the boundary bin (old k_scan).
__global__ __launch_bounds__(256) void k_hist_scan(const float* __restrict__ x,
                                                   const float* __restrict__ dc,
                                                   const int* __restrict__ kptr,
                                                   uint32_t* __restrict__ hist,
                                                   uint32_t* __restrict__ harr,
                                                   int2* __restrict__ rowmeta) {
    // Packed u16 counts: bin b lives in half (b&1) of word lh32[b>>1].
    // Max count/bin/block = 8*3136 = 25088 < 65536, so halves never carry.
    __shared__ uint32_t lh32[NBINS / 2];           // 16 KiB -> 8 blocks/CU
    __shared__ float sbf[8];
    __shared__ int lastflag;
    const int tid = threadIdx.x;
    const int row = blockIdx.x >> 4;
    const int c0 = (blockIdx.x & 15) * 8;
    const int K = *kptr;

    for (int i = tid; i < NBINS / 2; i += 256) lh32[i] = 0;
    if (tid < 8) sbf[tid] = boostf(dc, c0 + tid, K);
    __syncthreads();

    const float4* xp = (const float4*)(x + (size_t)row * NPR + (size_t)c0 * HW);
    const int nf4 = 8 * HW / 4;                    // 6272 (784 f4 per channel)
    int t = tid;
    for (; t + 256 < nf4; t += 512) {              // 2-way unrolled, independent loads
        float4 a = xp[t];
        float4 b = xp[t + 256];
        float fa = sbf[t / 784];
        float fb = sbf[(t + 256) / 784];
        uint32_t bx;
        bx = tokey(a.x * fa) >> BIN_SHIFT; atomicAdd(&lh32[bx >> 1], 1u << ((bx & 1) << 4));
        bx = tokey(a.y * fa) >> BIN_SHIFT; atomicAdd(&lh32[bx >> 1], 1u << ((bx & 1) << 4));
        bx = tokey(a.z * fa) >> BIN_SHIFT; atomicAdd(&lh32[bx >> 1], 1u << ((bx & 1) << 4));
        bx = tokey(a.w * fa) >> BIN_SHIFT; atomicAdd(&lh32[bx >> 1], 1u << ((bx & 1) << 4));
        bx = tokey(b.x * fb) >> BIN_SHIFT; atomicAdd(&lh32[bx >> 1], 1u << ((bx & 1) << 4));
        bx = tokey(b.y * fb) >> BIN_SHIFT; atomicAdd(&lh32[bx >> 1], 1u << ((bx & 1) << 4));
        bx = tokey(b.z * fb) >> BIN_SHIFT; atomicAdd(&lh32[bx >> 1], 1u << ((bx & 1) << 4));
        bx = tokey(b.w * fb) >> BIN_SHIFT; atomicAdd(&lh32[bx >> 1], 1u << ((bx & 1) << 4));
    }
    if (t < nf4) {
        float4 a = xp[t];
        float fa = sbf[t / 784];
        uint32_t bx;
        bx = tokey(a.x * fa) >> BIN_SHIFT; atomicAdd(&lh32[bx >> 1], 1u << ((bx & 1) << 4));
        bx = tokey(a.y * fa) >> BIN_SHIFT; atomicAdd(&lh32[bx >> 1], 1u << ((bx & 1) << 4));
        bx = tokey(a.z * fa) >> BIN_SHIFT; atomicAdd(&lh32[bx >> 1], 1u << ((bx & 1) << 4));
        bx = tokey(a.w * fa) >> BIN_SHIFT; atomicAdd(&lh32[bx >> 1], 1u << ((bx & 1) << 4));
    }
    __syncthreads();
    uint32_t* gh = hist + (size_t)row * NBINS;
    for (int i = tid; i < NBINS / 2; i += 256) {   // sparse unpacked flush (~200 hot bins)
        uint32_t w = lh32[i];
        if (w & 0xFFFFu) atomicAdd(&gh[2 * i], w & 0xFFFFu);
        if (w >> 16)     atomicAdd(&gh[2 * i + 1], w >> 16);
    }
    __threadfence();                               // release flushes before arrival
    if (tid == 0) lastflag = (atomicAdd(&harr[row], 1u) == 15u);
    __syncthreads();
    if (!lastflag) return;

    // ---- boundary scan for this row (16th arriver; all flushes visible) ----
    uint32_t* csum = lh32;                         // reuse LDS (hist already flushed)
    uint32_t Ku = (uint32_t)K;
    int hi = NBINS - 1 - 32 * tid;                 // chunk covers [hi-31, hi], descending
    uint32_t ssum = 0;
    for (int j = 0; j < 32; j++) ssum += aload32(&gh[hi - j]);
    csum[tid] = ssum;
    __syncthreads();
    for (int off = 1; off < 256; off <<= 1) {      // inclusive scan, descending-bin order
        uint32_t v = (tid >= off) ? csum[tid - off] : 0u;
        __syncthreads();
        csum[tid] += v;
        __syncthreads();
    }
    uint32_t incl = csum[tid];
    uint32_t excl = incl - ssum;
    if (excl < Ku && incl >= Ku) {                 // exactly one thread
        uint32_t cum = excl;
        for (int j = 0; j < 32; j++) {
            int b = hi - j;
            uint32_t h = aload32(&gh[b]);
            if (cum + h >= Ku) { rowmeta[row] = make_int2(b, (int)(Ku - cum)); break; }
            cum += h;
        }
    }
}

// ======== kernel 2: write pass + candidate compaction + per-row select ======
// Last-arriving block of each row runs the exact radix-select (old k_select,
// 256-thread variant proven on HW in the fused experiment).
__global__ __launch_bounds__(256) void k_write_sel(const float* __restrict__ x,
                                                   const float* __restrict__ dc,
                                                   const int* __restrict__ kptr,
                                                   const int2* __restrict__ rowmeta,
                                                   float* __restrict__ out,
                                                   unsigned long long* __restrict__ cand,
                                                   uint32_t* __restrict__ counters,
                                                   uint32_t* __restrict__ warr,
                                                   int cap) {
    const int tid = threadIdx.x;
    const int row = blockIdx.x >> 4;               // 64 rows x 16 groups of 8 channels
    const int c0 = (blockIdx.x & 15) * 8;
    const int bstar = rowmeta[row].x;              // written by previous dispatch

    __shared__ float sbf[8];
    __shared__ uint32_t lcnt, gbase;
    __shared__ unsigned long long lbuf[SELCAP];    // 16 KiB; reused as select buffer
    __shared__ uint32_t shist[256], ssufs[256];
    __shared__ uint32_t scnt;
    __shared__ int sh_d, sh_done, lastflag;
    if (tid == 0) lcnt = 0;
    if (tid < 8) sbf[tid] = boostf(dc, c0 + tid, *kptr);
    __syncthreads();

    size_t base = (size_t)row * NPR + (size_t)c0 * HW;
    const float4* xp = (const float4*)(x + base);  // L3-resident after pass 1
    vf4* op = (vf4*)(out + base);
    int jbase = c0 * HW;
    const int nf4 = 8 * HW / 4;                    // 6272

    int t = tid;
    for (; t + 256 < nf4; t += 512) {
        float4 a = xp[t];
        float4 b = xp[t + 256];
        float fa = sbf[t / 784];
        float fb = sbf[(t + 256) / 784];
        vf4 oa, ob;
        float* ai = (float*)&a;
        float* bi = (float*)&b;
        #pragma unroll
        for (int q = 0; q < 4; q++) {
            float xv = ai[q];
            uint32_t key = tokey(xv * fa);
            int bin = (int)(key >> BIN_SHIFT);
            oa[q] = (bin > bstar) ? xv : 0.0f;
            if (bin == bstar) {
                uint32_t j = (uint32_t)(jbase + 4 * t + q);
                unsigned long long packed =
                    ((unsigned long long)(key & KEY_LOW) << 32) | (uint32_t)(~j);
                uint32_t pos = atomicAdd(&lcnt, 1u);
                if (pos < (uint32_t)SELCAP) lbuf[pos] = packed;
                else {
                    uint32_t gp = atomicAdd(&counters[row], 1u);
                    if ((int)gp < cap) astore64(&cand[(size_t)row * cap + gp], packed);
                }
            }
        }
        #pragma unroll
        for (int q = 0; q < 4; q++) {
            float xv = bi[q];
            uint32_t key = tokey(xv * fb);
            int bin = (int)(key >> BIN_SHIFT);
            ob[q] = (bin > bstar) ? xv : 0.0f;
            if (bin == bstar) {
                uint32_t j = (uint32_t)(jbase + 4 * (t + 256) + q);
                unsigned long long packed =
                    ((unsigned long long)(key & KEY_LOW) << 32) | (uint32_t)(~j);
                uint32_t pos = atomicAdd(&lcnt, 1u);
                if (pos < (uint32_t)SELCAP) lbuf[pos] = packed;
                else {
                    uint32_t gp = atomicAdd(&counters[row], 1u);
                    if ((int)gp < cap) astore64(&cand[(size_t)row * cap + gp], packed);
                }
            }
        }
        __builtin_nontemporal_store(oa, &op[t]);   // keep x resident in L3
        __builtin_nontemporal_store(ob, &op[t + 256]);
    }
    if (t < nf4) {
        float4 a = xp[t];
        float fa = sbf[t / 784];
        vf4 oa;
        float* ai = (float*)&a;
        #pragma unroll
        for (int q = 0; q < 4; q++) {
            float xv = ai[q];
            uint32_t key = tokey(xv * fa);
            int bin = (int)(key >> BIN_SHIFT);
            oa[q] = (bin > bstar) ? xv : 0.0f;
            if (bin == bstar) {
                uint32_t j = (uint32_t)(jbase + 4 * t + q);
                unsigned long long packed =
                    ((unsigned long long)(key & KEY_LOW) << 32) | (uint32_t)(~j);
                uint32_t pos = atomicAdd(&lcnt, 1u);
                if (pos < (uint32_t)SELCAP) lbuf[pos] = packed;
                else {
                    uint32_t gp = atomicAdd(&counters[row], 1u);
                    if ((int)gp < cap) astore64(&cand[(size_t)row * cap + gp], packed);
                }
            }
        }
        __builtin_nontemporal_store(oa, &op[t]);
    }
    __syncthreads();
    uint32_t m = lcnt < (uint32_t)SELCAP ? lcnt : (uint32_t)SELCAP;
    if (tid == 0) gbase = atomicAdd(&counters[row], m);
    __syncthreads();
    for (uint32_t i = tid; i < m; i += 256) {
        uint32_t pos = gbase + i;
        if ((int)pos < cap) astore64(&cand[(size_t)row * cap + pos], lbuf[i]);
    }
    __threadfence();                               // release cand/out before arrival
    if (tid == 0) lastflag = (atomicAdd(&warr[row], 1u) == 15u);
    __syncthreads();
    if (!lastflag) return;

    // ---- exact radix-select for this row (16th arriver) ---------------------
    uint32_t cnt = aload32(&counters[row]);
    if ((int)cnt > cap) cnt = (uint32_t)cap;
    int E = rowmeta[row].y;
    const unsigned long long* cp = cand + (size_t)row * cap;

    unsigned long long prefix = 0ull, mask = 0ull, thr = 0ull;
    uint32_t remaining = (uint32_t)E;
    bool compacted = false;
    uint32_t csize = cnt;
    if (tid == 0) sh_done = 0;

    for (int shift = 48; shift >= 0; shift -= 8) {
        shist[tid] = 0;
        __syncthreads();
        if (!compacted) {
            for (uint32_t s = tid; s < cnt; s += 256) {
                unsigned long long v = aload64(&cp[s]);
                if ((v & mask) == prefix)
                    atomicAdd(&shist[(uint32_t)(v >> shift) & 255u], 1u);
            }
        } else {
            for (uint32_t s = tid; s < csize; s += 256)
                atomicAdd(&shist[(uint32_t)(lbuf[s] >> shift) & 255u], 1u);
        }
        __syncthreads();
        ssufs[tid] = shist[tid];
        __syncthreads();
        for (int off = 1; off < 256; off <<= 1) {  // suffix sums (descending scan)
            uint32_t add = (tid + off < 256) ? ssufs[tid + off] : 0u;
            __syncthreads();
            ssufs[tid] += add;
            __syncthreads();
        }
        {
            uint32_t sd = ssufs[tid];
            uint32_t sn = (tid < 255) ? ssufs[tid + 1] : 0u;
            if (sd >= remaining && sn < remaining) sh_d = tid;
        }
        __syncthreads();
        int d = sh_d;
        uint32_t cumG = (d < 255) ? ssufs[d + 1] : 0u;
        uint32_t binC = ssufs[d] - cumG;
        unsigned long long npref = prefix | ((unsigned long long)(uint32_t)d << shift);
        unsigned long long nmask = mask | (0xFFull << shift);
        bool done = (ssufs[d] == remaining);       // whole bin completes exactly
        if (done) {
            thr = npref;
            if (tid == 0) sh_done = 1;
        }
        remaining -= cumG;
        __syncthreads();                           // ssufs reads done; sh_done visible
        if (!sh_done && binC <= (uint32_t)SELCAP && shift > 0) {
            if (tid == 0) scnt = 0;
            __syncthreads();
            // Survivors are exactly {v : (v & nmask)==npref}: refilter from global.
            for (uint32_t s = tid; s < cnt; s += 256) {
                unsigned long long v = aload64(&cp[s]);
                if ((v & nmask) == npref) {
                    uint32_t p = atomicAdd(&scnt, 1u);
                    lbuf[p] = v;
                }
            }
            __syncthreads();
            csize = binC;
            compacted = true;
        }
        prefix = npref;
        mask = nmask;
        if (sh_done) break;
    }
    if (!sh_done) thr = prefix;                    // fully resolved (all v distinct)

    const float* xr = x + (size_t)row * NPR;
    float* orow = out + (size_t)row * NPR;
    for (uint32_t s = tid; s < cnt; s += 256) {
        unsigned long long v = aload64(&cp[s]);
        if (v >= thr) {
            uint32_t j = ~(uint32_t)v;
            orow[j] = xr[j];
        }
    }
}

extern "C" void kernel_launch(void* const* d_in, const int* in_sizes, int n_in,
                              void* d_out, int out_size, void* d_ws, size_t ws_size,
                              hipStream_t stream) {
    const float* x  = (const float*)d_in[0];
    const float* dc = (const float*)d_in[1];
    const int* kptr = (const int*)d_in[2];
    float* out = (float*)d_out;

    char* ws = (char*)d_ws;
    int2* rowmeta       = (int2*)(ws + ROWMETA_OFF);
    uint32_t* harr      = (uint32_t*)(ws + HARR_OFF);
    uint32_t* counters  = (uint32_t*)(ws + COUNTER_OFF);
    uint32_t* warr      = (uint32_t*)(ws + WARR_OFF);
    uint32_t* hist      = (uint32_t*)(ws + HIST_OFF);
    unsigned long long* cand = (unsigned long long*)(ws + CAND_OFF);

    size_t cap_sz = (ws_size > CAND_OFF) ? (ws_size - CAND_OFF) / ((size_t)BB * 8) : 0;
    if (cap_sz > 65536) cap_sz = 65536;
    int cap = (int)cap_sz;

    (void)hipMemsetAsync(ws, 0, CAND_OFF, stream); // zero meta + arrivals + hist
    k_hist_scan<<<BB * 16, 256, 0, stream>>>(x, dc, kptr, hist, harr, rowmeta);
    k_write_sel<<<BB * 16, 256, 0, stream>>>(x, dc, kptr, rowmeta, out, cand,
                                             counters, warr, cap);
}